// Round 5
// baseline (4488.756 us; speedup 1.0000x reference)
//
#include <hip/hip_runtime.h>
#include <hip/hip_fp16.h>

// Sizes fixed by the problem.
#define B_   64
#define T_   1024
#define H1_  128
#define H2_  256
#define TC_  256              // time-chunk for LSTM3/4
#define NCH  (T_ / TC_)       // 4 chunks
#define MCH  (B_ * TC_)       // 16384 rows per chunk per layer

#define WREG 92               // lstm_big: packed weight pairs in VGPRs per thread
#define WLDS 36               // lstm_big: packed weight pairs in LDS per thread

typedef unsigned int  u32;
typedef unsigned short u16;
typedef _Float16 half2_t __attribute__((ext_vector_type(2)));

__device__ __forceinline__ float fdot2(u32 w, u32 h, float acc) {
    // v_dot2_f32_f16: acc += w.lo*h.lo + w.hi*h.hi (fp32 accumulate)
    return __builtin_amdgcn_fdot2(__builtin_bit_cast(half2_t, w),
                                  __builtin_bit_cast(half2_t, h), acc, false);
}
__device__ __forceinline__ float2 up2(u32 p) {
    __half2 h = __builtin_bit_cast(__half2, p);
    return __half22float2(h);
}
__device__ __forceinline__ u32 pk2(float a, float b) {
    __half2 h = __floats2half2_rn(a, b);
    return __builtin_bit_cast(u32, h);
}
__device__ __forceinline__ float hf(u16 u) { return __half2float(__builtin_bit_cast(__half, u)); }
__device__ __forceinline__ u16 fh(float f) { return __builtin_bit_cast(u16, __float2half(f)); }
__device__ __forceinline__ float sigf(float x) { return 1.0f / (1.0f + expf(-x)); }

// ---------------------------------------------------------------------------
// Phase B: LSTM1 + LSTM2 (H=128). grid=128 (batch*2), block=512 (1 gate col).
// Wh packed fp16 in 64 VGPRs/thread; h packed fp16 in LDS; fdot2 inner loop.
// Per-step outputs staged in an LDS ring, flushed every 8 steps (coalesced u32
// stores) so barriers never drain a fresh global store (r4 stall). Cell update
// is computed redundantly by all 512 threads to hide transcendental latency.
// ---------------------------------------------------------------------------
__global__ __launch_bounds__(512) void lstm_small(
    const float* __restrict__ X, const float* __restrict__ cw, const float* __restrict__ cb,
    const float* __restrict__ Wi1, const float* __restrict__ Wh1, const float* __restrict__ b1,
    const float* __restrict__ Wi2, const float* __restrict__ Wh2, const float* __restrict__ b2,
    u16* __restrict__ x12)
{
    const int blk = blockIdx.x;
    const int b = blk >> 1;
    const int layer = blk & 1;
    const int j = threadIdx.x;

    const float* Wi = layer ? Wi2 : Wi1;
    const float* Wh = layer ? Wh2 : Wh1;
    const float* bb = layer ? b2 : b1;

    // fold conv into 4 taps + bias
    float W4[4];
#pragma unroll
    for (int kk = 0; kk < 4; ++kk) {
        float s = 0.f;
#pragma unroll
        for (int c = 0; c < 16; ++c) {
            int cc = layer ? (15 - c) : c;
            s += cw[kk * 16 + c] * Wi[cc * 512 + j];
        }
        W4[kk] = s;
    }
    float beff = bb[j];
#pragma unroll
    for (int c = 0; c < 16; ++c) {
        int cc = layer ? (15 - c) : c;
        beff += cb[c] * Wi[cc * 512 + j];
    }

    // packed fp16 recurrent weights: pair p = (Wh[2p][j], Wh[2p+1][j])
    u32 whp[64];
#pragma unroll
    for (int p = 0; p < 64; ++p)
        whp[p] = pk2(Wh[(2 * p) * 512 + j], Wh[(2 * p + 1) * 512 + j]);

    __shared__ __align__(16) u32 hbuf_pk[64];   // 128 h as packed fp16
    __shared__ float zbuf[512];
    __shared__ __align__(16) u16 ring[8][128];  // 8-step output ring
    u16* hb16 = (u16*)hbuf_pk;
    if (j < 128) hb16[j] = 0;
    float c_state = 0.f;

    const float* Xb = X + (size_t)b * T_;
    float xm1 = 0.f, x0 = Xb[0], xp1 = Xb[1], xp2 = Xb[2];
    __syncthreads();

    const uint4* hp4 = (const uint4*)hbuf_pk;
    u32* x12w = (u32*)x12;
    const int fl_s = j >> 6, fl_c = j & 63;     // flush row/col

    for (int t = 0; t < T_; ++t) {
        // prefetch next input early: latency hides under the fdot2 chain
        float xnext = (t + 3 < T_) ? Xb[t + 3] : 0.f;

        float za = beff + xm1 * W4[0] + x0 * W4[1] + xp1 * W4[2] + xp2 * W4[3];
        float zb = 0.f, zc = 0.f, zd = 0.f;
#pragma unroll
        for (int m = 0; m < 16; ++m) {
            uint4 hh = hp4[m];
            za = fdot2(whp[4 * m + 0], hh.x, za);
            zb = fdot2(whp[4 * m + 1], hh.y, zb);
            zc = fdot2(whp[4 * m + 2], hh.z, zc);
            zd = fdot2(whp[4 * m + 3], hh.w, zd);
        }
        float z = (za + zb) + (zc + zd);
        // own-gate nonlinearity (wave-uniform branch): g-gate is [256,384)
        zbuf[j] = (j >= 256 && j < 384) ? tanhf(z) : sigf(z);
        __syncthreads();

        // redundant cell update on all 512 threads (hides tanh/LDS latency)
        int u = j & 127;
        float gi = zbuf[u], gf = zbuf[128 + u], gg = zbuf[256 + u], go = zbuf[384 + u];
        c_state = gf * c_state + gi * gg;
        float h = go * tanhf(c_state);
        u16 hp = fh(h);
        if (j < 128) { hb16[u] = hp; ring[t & 7][u] = hp; }
        __syncthreads();

        if ((t & 7) == 7) {   // coalesced flush of 8 steps (256B per 64 lanes)
            u32 v = ((const u32*)ring)[j];
            x12w[((size_t)b * T_ + t - 7 + fl_s) * 128 + layer * 64 + fl_c] = v;
        }
        xm1 = x0; x0 = xp1; xp1 = xp2; xp2 = xnext;
    }
}

// ---------------------------------------------------------------------------
// Wh3/Wh4 (256 x 1024 fp32) -> packed fp16 pairs, layout [l][k2][j]:
//   wpk[l*131072 + k2*1024 + j] = half(Wh[2k2][j]) | half(Wh[2k2+1][j])<<16
// ---------------------------------------------------------------------------
__global__ void cvt_wh(const float* __restrict__ Wh3, const float* __restrict__ Wh4,
                       u32* __restrict__ wpk)
{
    int idx = blockIdx.x * 256 + threadIdx.x;   // < 262144
    int l = idx >> 17;
    int rem = idx & 131071;
    int k2 = rem >> 10;
    int j = rem & 1023;
    const float* W = l ? Wh4 : Wh3;
    wpk[idx] = pk2(W[(2 * k2) * 1024 + j], W[(2 * k2 + 1) * 1024 + j]);
}

// ---------------------------------------------------------------------------
// Tiled GEMM, 128x128 tile, 256 threads, 8x8/thread, K-tile 16. A is fp16.
// KREV: reverse B's K index (feature flip). CHUNK: A-row remap for time chunks.
// OUTMODE 0: out fp16 (acc+bias)    OUTMODE 1: out fp32 tanh(acc+bias)
// ---------------------------------------------------------------------------
template<int KREV, int OUTMODE, int CHUNK>
__global__ __launch_bounds__(256) void gemm128(
    const u16* __restrict__ A, const float* __restrict__ Bm,
    const float* __restrict__ bias, void* __restrict__ outv,
    int t0, int N, int K)
{
    __shared__ __align__(16) float Alds[16][132];
    __shared__ __align__(16) float Blds[16][128];
    const int tid = threadIdx.x;
    const int m0 = blockIdx.x * 128;
    const int n0 = blockIdx.y * 128;
    const int tm = tid >> 4, tn = tid & 15;
    const int ar = tid >> 1, ak = (tid & 1) * 8;
    const int bk = tid >> 4, bn = (tid & 15) * 8;

    int arow = m0 + ar;
    if (CHUNK) arow = (arow >> 8) * T_ + t0 + (arow & 255);

    float acc[8][8];
#pragma unroll
    for (int r = 0; r < 8; ++r)
#pragma unroll
        for (int c = 0; c < 8; ++c) acc[r][c] = 0.f;

    for (int k0 = 0; k0 < K; k0 += 16) {
        const u16* Ap = A + (size_t)arow * K + k0 + ak;
        uint4 u = *(const uint4*)Ap;
        float2 f0 = up2(u.x), f1 = up2(u.y), f2 = up2(u.z), f3 = up2(u.w);
        float av[8] = {f0.x, f0.y, f1.x, f1.y, f2.x, f2.y, f3.x, f3.y};

        int krow = KREV ? (K - 1 - (k0 + bk)) : (k0 + bk);
        const float* Bp = Bm + (size_t)krow * N + n0 + bn;
        float4 bv0 = *(const float4*)Bp;
        float4 bv1 = *(const float4*)(Bp + 4);
#pragma unroll
        for (int i = 0; i < 8; ++i) Alds[ak + i][ar] = av[i];
        *(float4*)&Blds[bk][bn] = bv0;
        *(float4*)&Blds[bk][bn + 4] = bv1;
        __syncthreads();
#pragma unroll
        for (int kk = 0; kk < 16; ++kk) {
            float a[8], bb8[8];
            *(float4*)a         = *(const float4*)&Alds[kk][tm * 8];
            *(float4*)(a + 4)   = *(const float4*)&Alds[kk][tm * 8 + 4];
            *(float4*)bb8       = *(const float4*)&Blds[kk][tn * 8];
            *(float4*)(bb8 + 4) = *(const float4*)&Blds[kk][tn * 8 + 4];
#pragma unroll
            for (int r = 0; r < 8; ++r)
#pragma unroll
                for (int c = 0; c < 8; ++c) acc[r][c] += a[r] * bb8[c];
        }
        __syncthreads();
    }

    float bv[8];
#pragma unroll
    for (int c = 0; c < 8; ++c) bv[c] = bias[n0 + tn * 8 + c];

    if (OUTMODE == 0) {
        u16* outp = (u16*)outv;
#pragma unroll
        for (int r = 0; r < 8; ++r) {
            u32 pk[4];
#pragma unroll
            for (int c2 = 0; c2 < 4; ++c2)
                pk[c2] = pk2(acc[r][2 * c2] + bv[2 * c2], acc[r][2 * c2 + 1] + bv[2 * c2 + 1]);
            uint4 st = make_uint4(pk[0], pk[1], pk[2], pk[3]);
            *(uint4*)(outp + (size_t)(m0 + tm * 8 + r) * N + n0 + tn * 8) = st;
        }
    } else {
        float* outp = (float*)outv;
#pragma unroll
        for (int r = 0; r < 8; ++r) {
            float v[8];
#pragma unroll
            for (int c = 0; c < 8; ++c) v[c] = tanhf(acc[r][c] + bv[c]);
            *(float4*)(outp + (size_t)(m0 + tm * 8 + r) * N + n0 + tn * 8)     = *(float4*)v;
            *(float4*)(outp + (size_t)(m0 + tm * 8 + r) * N + n0 + tn * 8 + 4) = *(float4*)(v + 4);
        }
    }
}

// ---------------------------------------------------------------------------
// Phase C: LSTM3 + LSTM4 (H=256) over one time chunk [t0, t0+TC_).
// grid=128 (batch*2), block=1024: thread j owns gate column j (of 1024).
// WREG=92 packed fp16 pairs in VGPRs + WLDS=36 in LDS per thread.
// pre prefetched one step ahead; enc staged in an 8-step LDS ring
// (coalesced u32 flush); redundant cell update on all 1024 threads.
// ---------------------------------------------------------------------------
__global__ __launch_bounds__(1024) void lstm_big(
    const u16* __restrict__ pre, const u32* __restrict__ wpk,
    float* __restrict__ state, u16* __restrict__ enc, int t0)
{
    const int blk = blockIdx.x;
    const int b = blk >> 1;
    const int layer = blk & 1;
    const int j = threadIdx.x;

    __shared__ u32 wlds[WLDS * 1024];           // 147456 B, uint2 pairs [q2][1024]
    __shared__ __align__(16) u32 hbuf_pk[128];  // 256 h as packed fp16
    __shared__ float zbuf[1024];
    __shared__ __align__(16) u16 ring[8][256];  // 8-step enc ring (4 KB)

    const u32* wp = wpk + (size_t)layer * 131072;  // [k2][j] packed fp16 pairs
    u32 wreg[WREG];
#pragma unroll
    for (int q = 0; q < WREG; ++q) wreg[q] = wp[q * 1024 + j];
    uint2* wl = (uint2*)wlds;
#pragma unroll
    for (int q2 = 0; q2 < WLDS / 2; ++q2)
        wl[q2 * 1024 + j] = make_uint2(wp[(WREG + 2 * q2) * 1024 + j],
                                       (WREG + 2 * q2 + 1 < 128) ? wp[(WREG + 2 * q2 + 1) * 1024 + j] : 0u);

    float* st = state + ((size_t)layer * B_ + b) * 512;
    u16* hb16 = (u16*)hbuf_pk;
    const int u = j & 255;
    float c_state = (t0 == 0) ? 0.f : st[u];        // redundant copy per thread
    float h_last  = (t0 == 0) ? 0.f : st[256 + u];
    if (j < 256) hb16[u] = fh(h_last);
    __syncthreads();

    const u16* prow = pre + (size_t)(layer * MCH + b * TC_) * 1024;
    u32* encw = (u32*)enc;
    const uint4* hp4 = (const uint4*)hbuf_pk;
    const int fl_s = j >> 7, fl_c = j & 127;        // flush row/col

    u16 pcur = prow[j];
    for (int tt = 0; tt < TC_; ++tt, prow += 1024) {
        // prefetch next pre row early: latency hides under the fdot2 chain
        u16 pnxt = (tt + 1 < TC_) ? prow[1024 + j] : (u16)0;

        float za = hf(pcur), zb = 0.f, zc = 0.f, zd = 0.f;
#pragma unroll
        for (int m = 0; m < WREG / 4; ++m) {       // pairs 0..91 from registers
            uint4 hh = hp4[m];
            za = fdot2(wreg[4 * m + 0], hh.x, za);
            zb = fdot2(wreg[4 * m + 1], hh.y, zb);
            zc = fdot2(wreg[4 * m + 2], hh.z, zc);
            zd = fdot2(wreg[4 * m + 3], hh.w, zd);
        }
#pragma unroll
        for (int m = 0; m < WLDS / 4; ++m) {       // pairs 92..127 from LDS
            uint4 hh = hp4[WREG / 4 + m];
            uint2 w0 = wl[(2 * m + 0) * 1024 + j];
            uint2 w1 = wl[(2 * m + 1) * 1024 + j];
            za = fdot2(w0.x, hh.x, za);
            zb = fdot2(w0.y, hh.y, zb);
            zc = fdot2(w1.x, hh.z, zc);
            zd = fdot2(w1.y, hh.w, zd);
        }
        float z = (za + zb) + (zc + zd);
        // own-gate nonlinearity, wave-uniform branch: g-gate is [512,768)
        zbuf[j] = (j >= 512 && j < 768) ? tanhf(z) : sigf(z);
        __syncthreads();

        // redundant cell update on all 1024 threads
        float gi = zbuf[u], gf = zbuf[256 + u], gg = zbuf[512 + u], go = zbuf[768 + u];
        c_state = gf * c_state + gi * gg;
        float h = go * tanhf(c_state);
        u16 hp = fh(h);
        h_last = h;
        if (j < 256) { hb16[u] = hp; ring[tt & 7][u] = hp; }
        __syncthreads();

        if ((tt & 7) == 7) {  // coalesced flush (512B per 128 lanes)
            u32 v = ((const u32*)ring)[j];
            encw[((size_t)b * T_ + t0 + tt - 7 + fl_s) * 256 + layer * 128 + fl_c] = v;
        }
        pcur = pnxt;
    }
    if (j < 256) { st[u] = c_state; st[256 + u] = h_last; }
}

// ---------------------------------------------------------------------------
// Attention pooling + head, one workgroup per batch.
// ---------------------------------------------------------------------------
__global__ __launch_bounds__(256) void attn_head(
    const float* __restrict__ S1, const u16* __restrict__ enc,
    const float* __restrict__ attV, const float* __restrict__ attVb,
    const float* __restrict__ d1W, const float* __restrict__ d1b,
    const float* __restrict__ d2W, const float* __restrict__ d2b,
    float* __restrict__ out)
{
    const int b = blockIdx.x;
    const int tid = threadIdx.x;
    const int lane = tid & 63, w = tid >> 6;

    __shared__ float sb[1024];
    __shared__ float red[32];
    __shared__ __align__(16) float ctx[512];
    __shared__ float h1s[128];

    float av0 = attV[lane], av1 = attV[64 + lane];
    const float* S1b = S1 + (size_t)b * T_ * 128;
    for (int it = 0; it < 256; ++it) {
        int t = it * 4 + w;
        const float* row = S1b + (size_t)t * 128;
        float p = row[lane] * av0 + row[64 + lane] * av1;
#pragma unroll
        for (int off = 32; off > 0; off >>= 1) p += __shfl_down(p, off);
        if (lane == 0) sb[t] = p + attVb[0];
    }
    __syncthreads();

    float mx = -3.0e38f;
#pragma unroll
    for (int q = 0; q < 4; ++q) mx = fmaxf(mx, sb[tid + 256 * q]);
#pragma unroll
    for (int off = 32; off > 0; off >>= 1) mx = fmaxf(mx, __shfl_down(mx, off));
    if (lane == 0) red[w] = mx;
    __syncthreads();
    if (tid == 0) red[8] = fmaxf(fmaxf(red[0], red[1]), fmaxf(red[2], red[3]));
    __syncthreads();
    float bm = red[8];
    float s = 0.f;
#pragma unroll
    for (int q = 0; q < 4; ++q) {
        float e = expf(sb[tid + 256 * q] - bm);
        sb[tid + 256 * q] = e;
        s += e;
    }
#pragma unroll
    for (int off = 32; off > 0; off >>= 1) s += __shfl_down(s, off);
    if (lane == 0) red[16 + w] = s;
    __syncthreads();
    if (tid == 0) red[24] = 1.0f / (red[16] + red[17] + red[18] + red[19]);
    __syncthreads();
    float inv = red[24];
#pragma unroll
    for (int q = 0; q < 4; ++q) sb[tid + 256 * q] *= inv;
    __syncthreads();

    const u16* encb = enc + (size_t)b * T_ * 512;
    float a0 = 0.f, a1 = 0.f;
    for (int t = 0; t < T_; ++t) {
        float wt = sb[t];
        a0 += wt * hf(encb[(size_t)t * 512 + tid]);
        a1 += wt * hf(encb[(size_t)t * 512 + 256 + tid]);
    }
    ctx[tid] = a0;
    ctx[256 + tid] = a1;
    __syncthreads();

    if (tid < 128) {
        float s1 = d1b[tid];
        for (int k = 0; k < 512; ++k) s1 += ctx[k] * d1W[k * 128 + tid];
        h1s[tid] = tanhf(s1);
    }
    __syncthreads();
    if (tid < 128) {
        float p = h1s[tid] * d2W[tid];
#pragma unroll
        for (int off = 32; off > 0; off >>= 1) p += __shfl_down(p, off);
        if ((tid & 63) == 0) red[28 + (tid >> 6)] = p;
    }
    __syncthreads();
    if (tid == 0) out[b] = red[28] + red[29] + d2b[0];
}

// ---------------------------------------------------------------------------
extern "C" void kernel_launch(void* const* d_in, const int* in_sizes, int n_in,
                              void* d_out, int out_size, void* d_ws, size_t ws_size,
                              hipStream_t stream)
{
    const float* X    = (const float*)d_in[0];
    const float* cw   = (const float*)d_in[1];
    const float* cb   = (const float*)d_in[2];
    const float* Wi1  = (const float*)d_in[3];
    const float* Wh1  = (const float*)d_in[4];
    const float* b1   = (const float*)d_in[5];
    const float* Wi2  = (const float*)d_in[6];
    const float* Wh2  = (const float*)d_in[7];
    const float* b2   = (const float*)d_in[8];
    const float* Wi3  = (const float*)d_in[9];
    const float* Wh3  = (const float*)d_in[10];
    const float* b3   = (const float*)d_in[11];
    const float* Wi4  = (const float*)d_in[12];
    const float* Wh4  = (const float*)d_in[13];
    const float* b4   = (const float*)d_in[14];
    const float* attW = (const float*)d_in[15];
    const float* attWb= (const float*)d_in[16];
    const float* attV = (const float*)d_in[17];
    const float* attVb= (const float*)d_in[18];
    const float* d1W  = (const float*)d_in[19];
    const float* d1b  = (const float*)d_in[20];
    const float* d2W  = (const float*)d_in[21];
    const float* d2b  = (const float*)d_in[22];
    float* out = (float*)d_out;

    // workspace layout (total 169,082,880 B ~ 161.3 MiB):
    char* w = (char*)d_ws;
    u16*   x12  = (u16*)w;                          // 64*1024*256*2      = 33,554,432
    u16*   pre  = (u16*)(w + 33554432);             // 2*16384*1024*2     = 67,108,864 (per chunk)
    u16*   enc  = (u16*)(w + 100663296);            // 64*1024*512*2      = 67,108,864
    u32*   wpk  = (u32*)(w + 167772160);            // 2*128*1024*4       =  1,048,576
    float* state= (float*)(w + 168820736);          // 2*64*512*4         =    262,144
    float* S1   = (float*)(w + 33554432);           // 65536*128*4 = 32 MiB, aliases pre (dead)

    lstm_small<<<128, 512, 0, stream>>>(X, cw, cb, Wi1, Wh1, b1, Wi2, Wh2, b2, x12);
    cvt_wh<<<1024, 256, 0, stream>>>(Wh3, Wh4, wpk);

    for (int c = 0; c < NCH; ++c) {
        int t0 = c * TC_;
        gemm128<0, 0, 1><<<dim3(128, 8), 256, 0, stream>>>(x12, Wi3, b3, pre, t0, 1024, 256);
        gemm128<1, 0, 1><<<dim3(128, 8), 256, 0, stream>>>(x12, Wi4, b4, pre + (size_t)MCH * 1024, t0, 1024, 256);
        lstm_big<<<128, 1024, 0, stream>>>(pre, wpk, state, enc, t0);
    }

    gemm128<0, 1, 0><<<dim3(512, 1), 256, 0, stream>>>(enc, attW, attWb, S1, 0, 128, 512);
    attn_head<<<64, 256, 0, stream>>>(S1, enc, attV, attVb, d1W, d1b, d2W, d2b, out);
}

// Round 6
// 4041.283 us; speedup vs baseline: 1.1107x; 1.1107x over previous
//
#include <hip/hip_runtime.h>
#include <hip/hip_fp16.h>

// Sizes fixed by the problem.
#define B_   64
#define T_   1024
#define H1_  128
#define H2_  256
#define TC_  256              // time-chunk for LSTM3/4
#define NCH  (T_ / TC_)       // 4 chunks
#define MCH  (B_ * TC_)       // 16384 rows per chunk per layer

#define WREG 23               // lstm_big: reg-resident weight pairs per gate (4*23=92)
#define WLDS 9                // lstm_big: LDS-resident weight pairs per gate (4*9=36)

typedef unsigned int  u32;
typedef unsigned short u16;
typedef _Float16 half2_t __attribute__((ext_vector_type(2)));

__device__ __forceinline__ float fdot2(u32 w, u32 h, float acc) {
    // v_dot2_f32_f16: acc += w.lo*h.lo + w.hi*h.hi (fp32 accumulate)
    return __builtin_amdgcn_fdot2(__builtin_bit_cast(half2_t, w),
                                  __builtin_bit_cast(half2_t, h), acc, false);
}
__device__ __forceinline__ float2 up2(u32 p) {
    __half2 h = __builtin_bit_cast(__half2, p);
    return __half22float2(h);
}
__device__ __forceinline__ u32 pk2(float a, float b) {
    __half2 h = __floats2half2_rn(a, b);
    return __builtin_bit_cast(u32, h);
}
__device__ __forceinline__ float hf(u16 u) { return __half2float(__builtin_bit_cast(__half, u)); }
__device__ __forceinline__ u16 fh(float f) { return __builtin_bit_cast(u16, __float2half(f)); }

// fast gate nonlinearities: v_exp_f32 + v_rcp_f32 (~1e-7 rel err, overflow-safe)
__device__ __forceinline__ float sigf(float x) {
    return __builtin_amdgcn_rcpf(1.0f + __expf(-x));
}
__device__ __forceinline__ float tanhf_fast(float x) {
    float e = __expf(-2.0f * fabsf(x));
    float t = (1.0f - e) * __builtin_amdgcn_rcpf(1.0f + e);
    return __builtin_copysignf(t, x);
}

// ---------------------------------------------------------------------------
// Phase B: LSTM1 + LSTM2 (H=128). grid=128 (batch*2), block=512.
// SPLIT-K decomposition: thread (u, s) computes ALL 4 gates of unit u over
// K-range s (32 h each); lane = s*16 + (u&15) so the 4 K-partials of a unit
// live in one wave -> 2x shfl_xor reduce, ONE barrier/step, no zbuf.
// Cell update redundant on all 4 s-copies (exec-masked cost is identical).
// Global h store issued at top of NEXT step so it drains before the barrier.
// ---------------------------------------------------------------------------
__global__ __launch_bounds__(512) void lstm_small(
    const float* __restrict__ X, const float* __restrict__ cw, const float* __restrict__ cb,
    const float* __restrict__ Wi1, const float* __restrict__ Wh1, const float* __restrict__ b1,
    const float* __restrict__ Wi2, const float* __restrict__ Wh2, const float* __restrict__ b2,
    u16* __restrict__ x12)
{
    const int blk = blockIdx.x;
    const int b = blk >> 1;
    const int layer = blk & 1;
    const int j = threadIdx.x;
    const int s = (j >> 4) & 3;                 // K-quarter
    const int u = ((j >> 6) << 4) | (j & 15);   // unit 0..127

    const float* Wi = layer ? Wi2 : Wi1;
    const float* Wh = layer ? Wh2 : Wh1;
    const float* bb = layer ? b2 : b1;

    // conv fold (4 taps + bias) for the 4 gate columns of unit u
    float W4g[4][4], beff[4];
#pragma unroll
    for (int g = 0; g < 4; ++g) {
        const int col = g * 128 + u;
#pragma unroll
        for (int kk = 0; kk < 4; ++kk) {
            float sacc = 0.f;
#pragma unroll
            for (int c = 0; c < 16; ++c) {
                int cc = layer ? (15 - c) : c;
                sacc += cw[kk * 16 + c] * Wi[cc * 512 + col];
            }
            W4g[g][kk] = sacc;
        }
        float be = bb[col];
#pragma unroll
        for (int c = 0; c < 16; ++c) {
            int cc = layer ? (15 - c) : c;
            be += cb[c] * Wi[cc * 512 + col];
        }
        beff[g] = be;
    }

    // packed fp16 recurrent weights: gate g, pair p -> k2 = s*16+p
    u32 wreg[64];
#pragma unroll
    for (int g = 0; g < 4; ++g)
#pragma unroll
        for (int p = 0; p < 16; ++p) {
            int k2 = s * 16 + p;
            int col = g * 128 + u;
            wreg[g * 16 + p] = pk2(Wh[(2 * k2) * 512 + col], Wh[(2 * k2 + 1) * 512 + col]);
        }

    // double-buffered h (packed fp16), padded per K-quarter to dodge conflicts
    __shared__ __align__(16) u16 hb[2][4][40];   // 32 h + 8 pad per seg
    if (s == 0) hb[0][u >> 5][u & 31] = 0;
    float c_state = 0.f;
    u16 hprev = 0;

    const float* Xb = X + (size_t)b * T_;
    float xm1 = 0.f, x0 = Xb[0], xp1 = Xb[1], xp2 = Xb[2];
    __syncthreads();

    int p = 0;
    for (int t = 0; t < T_; ++t) {
        // previous step's h store: issued early, drains during this step
        if (s == 0 && t > 0)
            x12[((size_t)b * T_ + t - 1) * 256 + layer * 128 + u] = hprev;
        float xnext = (t + 3 < T_) ? Xb[t + 3] : 0.f;

        const uint4* hp4 = (const uint4*)&hb[p][s][0];
        float vz0 = 0.f, vz1 = 0.f, vz2 = 0.f, vz3 = 0.f;
#pragma unroll
        for (int m = 0; m < 4; ++m) {
            uint4 hh = hp4[m];
            u32 hw[4] = {hh.x, hh.y, hh.z, hh.w};
#pragma unroll
            for (int c = 0; c < 4; ++c) {
                int idx = 4 * m + c;
                vz0 = fdot2(wreg[idx], hw[c], vz0);
                vz1 = fdot2(wreg[16 + idx], hw[c], vz1);
                vz2 = fdot2(wreg[32 + idx], hw[c], vz2);
                vz3 = fdot2(wreg[48 + idx], hw[c], vz3);
            }
        }
        // reduce the 4 K-partials across s (lane bits 4,5)
        vz0 += __shfl_xor(vz0, 16); vz0 += __shfl_xor(vz0, 32);
        vz1 += __shfl_xor(vz1, 16); vz1 += __shfl_xor(vz1, 32);
        vz2 += __shfl_xor(vz2, 16); vz2 += __shfl_xor(vz2, 32);
        vz3 += __shfl_xor(vz3, 16); vz3 += __shfl_xor(vz3, 32);

        float z0 = vz0 + beff[0] + xm1 * W4g[0][0] + x0 * W4g[0][1] + xp1 * W4g[0][2] + xp2 * W4g[0][3];
        float z1 = vz1 + beff[1] + xm1 * W4g[1][0] + x0 * W4g[1][1] + xp1 * W4g[1][2] + xp2 * W4g[1][3];
        float z2 = vz2 + beff[2] + xm1 * W4g[2][0] + x0 * W4g[2][1] + xp1 * W4g[2][2] + xp2 * W4g[2][3];
        float z3 = vz3 + beff[3] + xm1 * W4g[3][0] + x0 * W4g[3][1] + xp1 * W4g[3][2] + xp2 * W4g[3][3];

        float gi = sigf(z0), gf = sigf(z1), gg = tanhf_fast(z2), go = sigf(z3);
        c_state = gf * c_state + gi * gg;
        float h = go * tanhf_fast(c_state);
        hprev = fh(h);
        if (s == 0) hb[p ^ 1][u >> 5][u & 31] = hprev;
        __syncthreads();
        p ^= 1;
        xm1 = x0; x0 = xp1; xp1 = xp2; xp2 = xnext;
    }
    if (s == 0)
        x12[((size_t)b * T_ + T_ - 1) * 256 + layer * 128 + u] = hprev;
}

// ---------------------------------------------------------------------------
// Wh3/Wh4 (256 x 1024 fp32) -> packed fp16 pairs, layout [l][k2][j]:
//   wpk[l*131072 + k2*1024 + j] = half(Wh[2k2][j]) | half(Wh[2k2+1][j])<<16
// ---------------------------------------------------------------------------
__global__ void cvt_wh(const float* __restrict__ Wh3, const float* __restrict__ Wh4,
                       u32* __restrict__ wpk)
{
    int idx = blockIdx.x * 256 + threadIdx.x;   // < 262144
    int l = idx >> 17;
    int rem = idx & 131071;
    int k2 = rem >> 10;
    int j = rem & 1023;
    const float* W = l ? Wh4 : Wh3;
    wpk[idx] = pk2(W[(2 * k2) * 1024 + j], W[(2 * k2 + 1) * 1024 + j]);
}

// ---------------------------------------------------------------------------
// Tiled GEMM, 128x128 tile, 256 threads, 8x8/thread, K-tile 16. A is fp16.
// KREV: reverse B's K index (feature flip). CHUNK: A-row remap for time chunks.
// OUTMODE 0: out fp16 (acc+bias)    OUTMODE 1: out fp32 tanh(acc+bias)
// ---------------------------------------------------------------------------
template<int KREV, int OUTMODE, int CHUNK>
__global__ __launch_bounds__(256) void gemm128(
    const u16* __restrict__ A, const float* __restrict__ Bm,
    const float* __restrict__ bias, void* __restrict__ outv,
    int t0, int N, int K)
{
    __shared__ __align__(16) float Alds[16][132];
    __shared__ __align__(16) float Blds[16][128];
    const int tid = threadIdx.x;
    const int m0 = blockIdx.x * 128;
    const int n0 = blockIdx.y * 128;
    const int tm = tid >> 4, tn = tid & 15;
    const int ar = tid >> 1, ak = (tid & 1) * 8;
    const int bk = tid >> 4, bn = (tid & 15) * 8;

    int arow = m0 + ar;
    if (CHUNK) arow = (arow >> 8) * T_ + t0 + (arow & 255);

    float acc[8][8];
#pragma unroll
    for (int r = 0; r < 8; ++r)
#pragma unroll
        for (int c = 0; c < 8; ++c) acc[r][c] = 0.f;

    for (int k0 = 0; k0 < K; k0 += 16) {
        const u16* Ap = A + (size_t)arow * K + k0 + ak;
        uint4 u = *(const uint4*)Ap;
        float2 f0 = up2(u.x), f1 = up2(u.y), f2 = up2(u.z), f3 = up2(u.w);
        float av[8] = {f0.x, f0.y, f1.x, f1.y, f2.x, f2.y, f3.x, f3.y};

        int krow = KREV ? (K - 1 - (k0 + bk)) : (k0 + bk);
        const float* Bp = Bm + (size_t)krow * N + n0 + bn;
        float4 bv0 = *(const float4*)Bp;
        float4 bv1 = *(const float4*)(Bp + 4);
#pragma unroll
        for (int i = 0; i < 8; ++i) Alds[ak + i][ar] = av[i];
        *(float4*)&Blds[bk][bn] = bv0;
        *(float4*)&Blds[bk][bn + 4] = bv1;
        __syncthreads();
#pragma unroll
        for (int kk = 0; kk < 16; ++kk) {
            float a[8], bb8[8];
            *(float4*)a         = *(const float4*)&Alds[kk][tm * 8];
            *(float4*)(a + 4)   = *(const float4*)&Alds[kk][tm * 8 + 4];
            *(float4*)bb8       = *(const float4*)&Blds[kk][tn * 8];
            *(float4*)(bb8 + 4) = *(const float4*)&Blds[kk][tn * 8 + 4];
#pragma unroll
            for (int r = 0; r < 8; ++r)
#pragma unroll
                for (int c = 0; c < 8; ++c) acc[r][c] += a[r] * bb8[c];
        }
        __syncthreads();
    }

    float bv[8];
#pragma unroll
    for (int c = 0; c < 8; ++c) bv[c] = bias[n0 + tn * 8 + c];

    if (OUTMODE == 0) {
        u16* outp = (u16*)outv;
#pragma unroll
        for (int r = 0; r < 8; ++r) {
            u32 pk[4];
#pragma unroll
            for (int c2 = 0; c2 < 4; ++c2)
                pk[c2] = pk2(acc[r][2 * c2] + bv[2 * c2], acc[r][2 * c2 + 1] + bv[2 * c2 + 1]);
            uint4 st = make_uint4(pk[0], pk[1], pk[2], pk[3]);
            *(uint4*)(outp + (size_t)(m0 + tm * 8 + r) * N + n0 + tn * 8) = st;
        }
    } else {
        float* outp = (float*)outv;
#pragma unroll
        for (int r = 0; r < 8; ++r) {
            float v[8];
#pragma unroll
            for (int c = 0; c < 8; ++c) v[c] = tanhf(acc[r][c] + bv[c]);
            *(float4*)(outp + (size_t)(m0 + tm * 8 + r) * N + n0 + tn * 8)     = *(float4*)v;
            *(float4*)(outp + (size_t)(m0 + tm * 8 + r) * N + n0 + tn * 8 + 4) = *(float4*)(v + 4);
        }
    }
}

// ---------------------------------------------------------------------------
// Phase C: LSTM3 + LSTM4 (H=256) over one time chunk [t0, t0+TC_).
// grid=128 (batch*2), block=1024. SPLIT-K: thread (u, s) computes all 4 gates
// of unit u over K-range s (64 h). lane = s*16+(u&15) -> shfl_xor(16,32)
// reduce, ONE barrier/step. Weights: 92 pairs in VGPRs + 36 in LDS [q][j].
// pre staged via double-buffered LDS row (coalesced 1 u16/thread prefetch).
// ---------------------------------------------------------------------------
__global__ __launch_bounds__(1024) void lstm_big(
    const u16* __restrict__ pre, const u32* __restrict__ wpk,
    float* __restrict__ state, u16* __restrict__ enc, int t0)
{
    const int blk = blockIdx.x;
    const int b = blk >> 1;
    const int layer = blk & 1;
    const int j = threadIdx.x;
    const int s = (j >> 4) & 3;                 // K-quarter
    const int u = ((j >> 6) << 4) | (j & 15);   // unit 0..255

    __shared__ u32 wlds[4 * WLDS * 1024];        // 147456 B, [q][j]
    __shared__ __align__(16) u16 hb[2][4][72];   // 64 h + 8 pad per seg, dbuf
    __shared__ u16 stage[2][1024];               // pre-row double buffer

    const u32* wp = wpk + (size_t)layer * 131072;  // [k2][1024] packed fp16 pairs
    u32 wreg[4 * WREG];
#pragma unroll
    for (int g = 0; g < 4; ++g)
#pragma unroll
        for (int pp = 0; pp < 32; ++pp) {
            u32 v = wp[(s * 32 + pp) * 1024 + g * 256 + u];
            if (pp < WREG) wreg[g * WREG + pp] = v;
            else           wlds[(g * WLDS + pp - WREG) * 1024 + j] = v;
        }

    float* st = state + ((size_t)layer * B_ + b) * 512;
    float c_state = (t0 == 0) ? 0.f : st[u];
    float h0      = (t0 == 0) ? 0.f : st[256 + u];
    if (s == 0) hb[0][u >> 6][u & 63] = fh(h0);

    const u16* prow = pre + (size_t)(layer * MCH + b * TC_) * 1024;
    stage[0][j] = prow[j];
    __syncthreads();

    u16 hprev = 0;
    float h_lastf = h0;
    int p = 0;
    for (int tt = 0; tt < TC_; ++tt) {
        // previous step's enc store: issued early, drains during this step
        if (s == 0 && tt > 0)
            enc[((size_t)b * T_ + t0 + tt - 1) * 512 + layer * 256 + u] = hprev;
        // coalesced prefetch of next pre row
        u16 pn = (tt + 1 < TC_) ? prow[(tt + 1) * 1024 + j] : (u16)0;
        // own 4 gate inputs from the staged row
        float zin0 = hf(stage[p][u]);
        float zin1 = hf(stage[p][256 + u]);
        float zin2 = hf(stage[p][512 + u]);
        float zin3 = hf(stage[p][768 + u]);

        const uint4* hp4 = (const uint4*)&hb[p][s][0];
        float vz0 = 0.f, vz1 = 0.f, vz2 = 0.f, vz3 = 0.f;
#pragma unroll
        for (int m = 0; m < 8; ++m) {
            uint4 hh = hp4[m];
            u32 hw[4] = {hh.x, hh.y, hh.z, hh.w};
#pragma unroll
            for (int c = 0; c < 4; ++c) {
                const int idx = 4 * m + c;
                u32 w0 = (idx < WREG) ? wreg[0 * WREG + idx] : wlds[(0 * WLDS + idx - WREG) * 1024 + j];
                u32 w1 = (idx < WREG) ? wreg[1 * WREG + idx] : wlds[(1 * WLDS + idx - WREG) * 1024 + j];
                u32 w2 = (idx < WREG) ? wreg[2 * WREG + idx] : wlds[(2 * WLDS + idx - WREG) * 1024 + j];
                u32 w3 = (idx < WREG) ? wreg[3 * WREG + idx] : wlds[(3 * WLDS + idx - WREG) * 1024 + j];
                vz0 = fdot2(w0, hw[c], vz0);
                vz1 = fdot2(w1, hw[c], vz1);
                vz2 = fdot2(w2, hw[c], vz2);
                vz3 = fdot2(w3, hw[c], vz3);
            }
        }
        stage[p ^ 1][j] = pn;   // publish next row (readers wait at barrier)

        vz0 += __shfl_xor(vz0, 16); vz0 += __shfl_xor(vz0, 32);
        vz1 += __shfl_xor(vz1, 16); vz1 += __shfl_xor(vz1, 32);
        vz2 += __shfl_xor(vz2, 16); vz2 += __shfl_xor(vz2, 32);
        vz3 += __shfl_xor(vz3, 16); vz3 += __shfl_xor(vz3, 32);

        float gi = sigf(vz0 + zin0), gf = sigf(vz1 + zin1);
        float gg = tanhf_fast(vz2 + zin2), go = sigf(vz3 + zin3);
        c_state = gf * c_state + gi * gg;
        float h = go * tanhf_fast(c_state);
        h_lastf = h;
        hprev = fh(h);
        if (s == 0) hb[p ^ 1][u >> 6][u & 63] = hprev;
        __syncthreads();
        p ^= 1;
    }
    if (s == 0) {
        enc[((size_t)b * T_ + t0 + TC_ - 1) * 512 + layer * 256 + u] = hprev;
        st[u] = c_state;
        st[256 + u] = h_lastf;
    }
}

// ---------------------------------------------------------------------------
// Attention pooling + head, one workgroup per batch.
// ---------------------------------------------------------------------------
__global__ __launch_bounds__(256) void attn_head(
    const float* __restrict__ S1, const u16* __restrict__ enc,
    const float* __restrict__ attV, const float* __restrict__ attVb,
    const float* __restrict__ d1W, const float* __restrict__ d1b,
    const float* __restrict__ d2W, const float* __restrict__ d2b,
    float* __restrict__ out)
{
    const int b = blockIdx.x;
    const int tid = threadIdx.x;
    const int lane = tid & 63, w = tid >> 6;

    __shared__ float sb[1024];
    __shared__ float red[32];
    __shared__ __align__(16) float ctx[512];
    __shared__ float h1s[128];

    float av0 = attV[lane], av1 = attV[64 + lane];
    const float* S1b = S1 + (size_t)b * T_ * 128;
    for (int it = 0; it < 256; ++it) {
        int t = it * 4 + w;
        const float* row = S1b + (size_t)t * 128;
        float p = row[lane] * av0 + row[64 + lane] * av1;
#pragma unroll
        for (int off = 32; off > 0; off >>= 1) p += __shfl_down(p, off);
        if (lane == 0) sb[t] = p + attVb[0];
    }
    __syncthreads();

    float mx = -3.0e38f;
#pragma unroll
    for (int q = 0; q < 4; ++q) mx = fmaxf(mx, sb[tid + 256 * q]);
#pragma unroll
    for (int off = 32; off > 0; off >>= 1) mx = fmaxf(mx, __shfl_down(mx, off));
    if (lane == 0) red[w] = mx;
    __syncthreads();
    if (tid == 0) red[8] = fmaxf(fmaxf(red[0], red[1]), fmaxf(red[2], red[3]));
    __syncthreads();
    float bm = red[8];
    float s = 0.f;
#pragma unroll
    for (int q = 0; q < 4; ++q) {
        float e = expf(sb[tid + 256 * q] - bm);
        sb[tid + 256 * q] = e;
        s += e;
    }
#pragma unroll
    for (int off = 32; off > 0; off >>= 1) s += __shfl_down(s, off);
    if (lane == 0) red[16 + w] = s;
    __syncthreads();
    if (tid == 0) red[24] = 1.0f / (red[16] + red[17] + red[18] + red[19]);
    __syncthreads();
    float inv = red[24];
#pragma unroll
    for (int q = 0; q < 4; ++q) sb[tid + 256 * q] *= inv;
    __syncthreads();

    const u16* encb = enc + (size_t)b * T_ * 512;
    float a0 = 0.f, a1 = 0.f;
    for (int t = 0; t < T_; ++t) {
        float wt = sb[t];
        a0 += wt * hf(encb[(size_t)t * 512 + tid]);
        a1 += wt * hf(encb[(size_t)t * 512 + 256 + tid]);
    }
    ctx[tid] = a0;
    ctx[256 + tid] = a1;
    __syncthreads();

    if (tid < 128) {
        float s1 = d1b[tid];
        for (int k = 0; k < 512; ++k) s1 += ctx[k] * d1W[k * 128 + tid];
        h1s[tid] = tanhf(s1);
    }
    __syncthreads();
    if (tid < 128) {
        float p = h1s[tid] * d2W[tid];
#pragma unroll
        for (int off = 32; off > 0; off >>= 1) p += __shfl_down(p, off);
        if ((tid & 63) == 0) red[28 + (tid >> 6)] = p;
    }
    __syncthreads();
    if (tid == 0) out[b] = red[28] + red[29] + d2b[0];
}

// ---------------------------------------------------------------------------
extern "C" void kernel_launch(void* const* d_in, const int* in_sizes, int n_in,
                              void* d_out, int out_size, void* d_ws, size_t ws_size,
                              hipStream_t stream)
{
    const float* X    = (const float*)d_in[0];
    const float* cw   = (const float*)d_in[1];
    const float* cb   = (const float*)d_in[2];
    const float* Wi1  = (const float*)d_in[3];
    const float* Wh1  = (const float*)d_in[4];
    const float* b1   = (const float*)d_in[5];
    const float* Wi2  = (const float*)d_in[6];
    const float* Wh2  = (const float*)d_in[7];
    const float* b2   = (const float*)d_in[8];
    const float* Wi3  = (const float*)d_in[9];
    const float* Wh3  = (const float*)d_in[10];
    const float* b3   = (const float*)d_in[11];
    const float* Wi4  = (const float*)d_in[12];
    const float* Wh4  = (const float*)d_in[13];
    const float* b4   = (const float*)d_in[14];
    const float* attW = (const float*)d_in[15];
    const float* attWb= (const float*)d_in[16];
    const float* attV = (const float*)d_in[17];
    const float* attVb= (const float*)d_in[18];
    const float* d1W  = (const float*)d_in[19];
    const float* d1b  = (const float*)d_in[20];
    const float* d2W  = (const float*)d_in[21];
    const float* d2b  = (const float*)d_in[22];
    float* out = (float*)d_out;

    // workspace layout (total 169,082,880 B ~ 161.3 MiB):
    char* w = (char*)d_ws;
    u16*   x12  = (u16*)w;                          // 64*1024*256*2      = 33,554,432
    u16*   pre  = (u16*)(w + 33554432);             // 2*16384*1024*2     = 67,108,864 (per chunk)
    u16*   enc  = (u16*)(w + 100663296);            // 64*1024*512*2      = 67,108,864
    u32*   wpk  = (u32*)(w + 167772160);            // 2*128*1024*4       =  1,048,576
    float* state= (float*)(w + 168820736);          // 2*64*512*4         =    262,144
    float* S1   = (float*)(w + 33554432);           // 65536*128*4 = 32 MiB, aliases pre (dead)

    lstm_small<<<128, 512, 0, stream>>>(X, cw, cb, Wi1, Wh1, b1, Wi2, Wh2, b2, x12);
    cvt_wh<<<1024, 256, 0, stream>>>(Wh3, Wh4, wpk);

    for (int c = 0; c < NCH; ++c) {
        int t0 = c * TC_;
        gemm128<0, 0, 1><<<dim3(128, 8), 256, 0, stream>>>(x12, Wi3, b3, pre, t0, 1024, 256);
        gemm128<1, 0, 1><<<dim3(128, 8), 256, 0, stream>>>(x12, Wi4, b4, pre + (size_t)MCH * 1024, t0, 1024, 256);
        lstm_big<<<128, 1024, 0, stream>>>(pre, wpk, state, enc, t0);
    }

    gemm128<0, 1, 0><<<dim3(512, 1), 256, 0, stream>>>(enc, attW, attWb, S1, 0, 128, 512);
    attn_head<<<64, 256, 0, stream>>>(S1, enc, attV, attVb, d1W, d1b, d2W, d2b, out);
}